// Round 7
// baseline (716.374 us; speedup 1.0000x reference)
//
#include <hip/hip_runtime.h>
#include <hip/hip_bf16.h>
#include <hip/hip_fp16.h>

#define SLOPE 0.2f

typedef __attribute__((ext_vector_type(8))) short bf16x8;
typedef __attribute__((ext_vector_type(4))) float f32x4;

__device__ __forceinline__ unsigned short bf16_rn(float f) {
    unsigned u = __float_as_uint(f);
    return (unsigned short)((u + 0x7FFFu + ((u >> 16) & 1u)) >> 16);
}
__device__ __forceinline__ float bf16_to_f32(unsigned short s) {
    return __uint_as_float(((unsigned)s) << 16);
}

// ---------------- fat prep: W split into fragment-order bf16 hi/lo tables + edge histogram ----
// W table layout per matrix (16384 hi + 16384 lo, interleaved per layer):
//   chunk address for (n, k): ks=k>>5, q=(k>>3)&3, j=k&7 -> ((ks*4+q)*128 + n)*8 + j
// so a B-fragment (lane ml, quad q, tile nt, chunk ks) is one contiguous, coalesced 16B load.

__global__ __launch_bounds__(256) void fat_prep(const float* __restrict__ W0, const float* __restrict__ W1,
                                                const float* __restrict__ W2, const float* __restrict__ W3,
                                                const float* __restrict__ W4, const float* __restrict__ W5,
                                                unsigned short* __restrict__ Wtab,
                                                const int* __restrict__ dstv, int* __restrict__ deg, int E) {
    int b = blockIdx.x, t = threadIdx.x;
    if (b < 384) {
        int j = b >> 6;                  // matrix 0..5
        int e = ((b & 63) << 8) + t;     // 0..16383
        const float* W = (j == 0) ? W0 : (j == 1) ? W1 : (j == 2) ? W2
                       : (j == 3) ? W3 : (j == 4) ? W4 : W5;
        int L = j >> 1, side = j & 1;
        unsigned short* hiT = Wtab + (size_t)L * 65536 + side * 16384;
        unsigned short* loT = hiT + 32768;
        int n = e >> 7, k = e & 127;
        float x = W[k * 128 + n];
        unsigned short h = bf16_rn(x);
        int ks = k >> 5, q = (k >> 3) & 3, jj = k & 7;
        int off = ((ks * 4 + q) * 128 + n) * 8 + jj;
        hiT[off] = h;
        loT[off] = bf16_rn(x - bf16_to_f32(h));
    } else {
        int i = (b - 384) * 256 + t;     // histogram: fire-and-forget atomics
        if (i < E) atomicAdd(&deg[dstv[i]], 1);
    }
}

// ---------------- scan ----------------

__global__ __launch_bounds__(256) void k_scan(const int* __restrict__ in, int* __restrict__ out,
                                              int* bsums, int n) {
    __shared__ int wsum[4];
    int t = threadIdx.x;
    int base = blockIdx.x * 1024 + t * 4;
    int v0 = (base + 0 < n) ? in[base + 0] : 0;
    int v1 = (base + 1 < n) ? in[base + 1] : 0;
    int v2 = (base + 2 < n) ? in[base + 2] : 0;
    int v3 = (base + 3 < n) ? in[base + 3] : 0;
    int tsum = v0 + v1 + v2 + v3;
    int lane = t & 63, wid = t >> 6;
    int x = tsum;
    #pragma unroll
    for (int d = 1; d < 64; d <<= 1) {
        int y = __shfl_up(x, d);
        if (lane >= d) x += y;
    }
    if (lane == 63) wsum[wid] = x;
    __syncthreads();
    if (t == 0) {
        int a = 0;
        for (int w = 0; w < 4; ++w) { int b = wsum[w]; wsum[w] = a; a += b; }
    }
    __syncthreads();
    int excl = x - tsum + wsum[wid];
    if (base + 0 < n) out[base + 0] = excl;
    if (base + 1 < n) out[base + 1] = excl + v0;
    if (base + 2 < n) out[base + 2] = excl + v0 + v1;
    if (base + 3 < n) out[base + 3] = excl + v0 + v1 + v2;
    if (bsums != nullptr && t == 255) bsums[blockIdx.x] = excl + tsum;
}

__global__ __launch_bounds__(256) void k_scan_add(const int* __restrict__ dscan,
                                                  const int* __restrict__ boff,
                                                  int* __restrict__ rowptr, int* __restrict__ cursor,
                                                  int n, int total) {
    int i = blockIdx.x * 256 + threadIdx.x;
    if (i < n) {
        int v = dscan[i] + boff[i >> 10];
        rowptr[i] = v;
        cursor[i] = v;
    }
    if (i == n) rowptr[n] = total;
}

// ---------------- MFMA GEMM block (bf16x3): A hi/lo staged in 20KB LDS, B direct from L2 ----

__device__ __forceinline__ void gemm_block(const float* __restrict__ X,
                                           const unsigned short* __restrict__ WL,
                                           __half* __restrict__ Y0, float* __restrict__ Y1,
                                           int M, int tile, int ysel,
                                           unsigned char* lds, int t) {
    const unsigned short* wb = WL + ysel * 16384;   // hi table; +32768 = lo table
    int row0 = tile * 128;
    int lane = t & 63, w = t >> 6;
    int ml = lane & 15, q = lane >> 4;
    int sm = t >> 1, sh = t & 1;
    int srow = row0 + sm;
    bool svalid = srow < M;

    f32x4 acc[2][8];
    #pragma unroll
    for (int i = 0; i < 2; ++i)
        #pragma unroll
        for (int j = 0; j < 8; ++j) acc[i][j] = (f32x4){0.f, 0.f, 0.f, 0.f};

    for (int ks = 0; ks < 4; ++ks) {
        int k0 = ks * 32;
        // ---- stage A (fp32 -> bf16 hi/lo), 80B row stride ----
        {
            float v[16];
            if (svalid) {
                const float* src = X + (size_t)srow * 128 + k0 + sh * 16;
                *(float4*)&v[0]  = *(const float4*)&src[0];
                *(float4*)&v[4]  = *(const float4*)&src[4];
                *(float4*)&v[8]  = *(const float4*)&src[8];
                *(float4*)&v[12] = *(const float4*)&src[12];
            } else {
                #pragma unroll
                for (int j = 0; j < 16; ++j) v[j] = 0.f;
            }
            unsigned hw[8], lw[8];
            #pragma unroll
            for (int j = 0; j < 8; ++j) {
                unsigned short h0 = bf16_rn(v[2 * j]);
                unsigned short h1 = bf16_rn(v[2 * j + 1]);
                unsigned short l0 = bf16_rn(v[2 * j] - bf16_to_f32(h0));
                unsigned short l1 = bf16_rn(v[2 * j + 1] - bf16_to_f32(h1));
                hw[j] = (unsigned)h0 | ((unsigned)h1 << 16);
                lw[j] = (unsigned)l0 | ((unsigned)l1 << 16);
            }
            unsigned char* pa = lds + sm * 80 + sh * 32;
            *(uint4*)(pa)      = *(uint4*)&hw[0];
            *(uint4*)(pa + 16) = *(uint4*)&hw[4];
            unsigned char* pl = lds + 10240 + sm * 80 + sh * 32;
            *(uint4*)(pl)      = *(uint4*)&lw[0];
            *(uint4*)(pl + 16) = *(uint4*)&lw[4];
        }
        __syncthreads();
        bf16x8 ah[2], al[2];
        #pragma unroll
        for (int mt = 0; mt < 2; ++mt) {
            int am = w * 32 + mt * 16 + ml;
            ah[mt] = *(const bf16x8*)(lds + am * 80 + q * 16);
            al[mt] = *(const bf16x8*)(lds + 10240 + am * 80 + q * 16);
        }
        const unsigned short* wrow = wb + ((ks * 4 + q) * 128) * 8;
        #pragma unroll
        for (int nt = 0; nt < 8; ++nt) {
            int n = nt * 16 + ml;
            bf16x8 bh = *(const bf16x8*)(wrow + n * 8);
            bf16x8 bl = *(const bf16x8*)(wrow + 32768 + n * 8);
            #pragma unroll
            for (int mt = 0; mt < 2; ++mt) {
                acc[mt][nt] = __builtin_amdgcn_mfma_f32_16x16x32_bf16(ah[mt], bh, acc[mt][nt], 0, 0, 0);
                acc[mt][nt] = __builtin_amdgcn_mfma_f32_16x16x32_bf16(ah[mt], bl, acc[mt][nt], 0, 0, 0);
                acc[mt][nt] = __builtin_amdgcn_mfma_f32_16x16x32_bf16(al[mt], bh, acc[mt][nt], 0, 0, 0);
            }
        }
        __syncthreads();
    }

    if (ysel == 0) {
        #pragma unroll
        for (int mt = 0; mt < 2; ++mt) {
            int rbase = row0 + w * 32 + mt * 16 + q * 4;
            #pragma unroll
            for (int r = 0; r < 4; ++r) {
                int row = rbase + r;
                if (row < M) {
                    #pragma unroll
                    for (int nt = 0; nt < 8; ++nt)
                        Y0[(size_t)row * 128 + nt * 16 + ml] = __float2half(acc[mt][nt][r]);
                }
            }
        }
    } else {
        #pragma unroll
        for (int mt = 0; mt < 2; ++mt) {
            int rbase = row0 + w * 32 + mt * 16 + q * 4;
            #pragma unroll
            for (int r = 0; r < 4; ++r) {
                int row = rbase + r;
                if (row < M) {
                    #pragma unroll
                    for (int nt = 0; nt < 8; ++nt)
                        Y1[(size_t)row * 128 + nt * 16 + ml] = acc[mt][nt][r];
                }
            }
        }
    }
}

__global__ __launch_bounds__(256) void k_gemm(const float* __restrict__ X,
                                              const unsigned short* __restrict__ WL,
                                              __half* __restrict__ Y0, float* __restrict__ Y1, int M) {
    __shared__ __align__(16) unsigned char lds[20480];
    gemm_block(X, WL, Y0, Y1, M, blockIdx.x, blockIdx.y, lds, threadIdx.x);
}

// ---- fat: CSR fill (1 edge/thread, latency-bound) + gemm layer 1 (MFMA-bound), co-scheduled ----

__global__ __launch_bounds__(256) void fat_gf(const float* __restrict__ X,
                                              const unsigned short* __restrict__ WL,
                                              __half* __restrict__ Y0, float* __restrict__ Y1, int M,
                                              const int* __restrict__ srcv, const int* __restrict__ dstv,
                                              int* __restrict__ cursor, int* __restrict__ col, int E) {
    __shared__ __align__(16) unsigned char lds[20480];
    int fb = (E + 255) >> 8;
    int b = blockIdx.x;
    if (b < fb) {
        int i = b * 256 + threadIdx.x;
        if (i < E) {
            int d = dstv[i];
            int p = atomicAdd(&cursor[d], 1);
            col[p] = srcv[i];
        }
    } else {
        int g = b - fb;
        int tiles = (M + 127) >> 7;
        gemm_block(X, WL, Y0, Y1, M, g % tiles, g / tiles, lds, threadIdx.x);
    }
}

// ---------------- fused attention: 4 dsts per wave, analytic self-loop ----------------

__device__ __forceinline__ float quadsum(float t) {
    t += __int_as_float(__builtin_amdgcn_update_dpp(0, __float_as_int(t), 0xB1, 0xf, 0xf, true)); // [1,0,3,2]
    t += __int_as_float(__builtin_amdgcn_update_dpp(0, __float_as_int(t), 0x4E, 0xf, 0xf, true)); // [2,3,0,1]
    return t;
}

template <bool MEAN>
__global__ __launch_bounds__(256) void fused_gat(const __half* __restrict__ XLh,
                                                 const float* __restrict__ XR,
                                                 const float* __restrict__ att,
                                                 const float* __restrict__ bias,
                                                 const int* __restrict__ rowptr,
                                                 const int* __restrict__ col,
                                                 float* __restrict__ OUT, int N) {
    int wave = (blockIdx.x * blockDim.x + threadIdx.x) >> 6;
    int lane = threadIdx.x & 63;
    int g = lane >> 4, sub = lane & 15;
    int dst = wave * 4 + g;
    bool vd = dst < N;
    int d0 = vd ? dst : 0;

    int start = vd ? rowptr[d0] : 0;
    int end   = vd ? rowptr[d0 + 1] : 0;

    float xr[8], av[8];
    {
        const float* xrp = &XR[(size_t)d0 * 128 + sub * 8];
        *(float4*)&xr[0] = *(const float4*)&xrp[0];
        *(float4*)&xr[4] = *(const float4*)&xrp[4];
        *(float4*)&av[0] = *(const float4*)&att[sub * 8];
        *(float4*)&av[4] = *(const float4*)&att[sub * 8 + 4];
    }

    int deg = end - start;
    int md = max(deg, __shfl_xor(deg, 16));
    md = max(md, __shfl_xor(md, 32));

    float acc[8];
    float s;
    // ---- analytic self-loop ----
    {
        uint4 r = *(const uint4*)&XLh[(size_t)d0 * 128 + sub * 8];
        float xs[8];
        const __half2* h = (const __half2*)&r;
        #pragma unroll
        for (int qq = 0; qq < 4; ++qq) {
            float2 f = __half22float2(h[qq]);
            xs[2 * qq] = f.x; xs[2 * qq + 1] = f.y;
        }
        float dS = 0.f;
        #pragma unroll
        for (int j = 0; j < 8; ++j) {
            float u = xs[j] + xr[j];
            u = fmaxf(u, SLOPE * u);
            dS = fmaf(u, av[j], dS);
        }
        float tS = quadsum(dS);
        float wS = __expf(fminf(tS, 80.f));
        s = wS;
        #pragma unroll
        for (int j = 0; j < 8; ++j) acc[j] = wS * xs[j];
    }

    for (int i = 0; i < md; i += 2) {
        int pA = start + i, pB = start + i + 1;
        bool vA = pA < end, vB = pB < end;
        int iA = col[vA ? pA : 0];
        int iB = col[vB ? pB : 0];
        uint4 rA = *(const uint4*)&XLh[(size_t)iA * 128 + sub * 8];
        uint4 rB = *(const uint4*)&XLh[(size_t)iB * 128 + sub * 8];
        float xA[8], xB[8];
        {
            const __half2* hA = (const __half2*)&rA;
            const __half2* hB = (const __half2*)&rB;
            #pragma unroll
            for (int qq = 0; qq < 4; ++qq) {
                float2 fA = __half22float2(hA[qq]);
                float2 fB = __half22float2(hB[qq]);
                xA[2 * qq] = fA.x; xA[2 * qq + 1] = fA.y;
                xB[2 * qq] = fB.x; xB[2 * qq + 1] = fB.y;
            }
        }
        float dA = 0.f, dB = 0.f;
        #pragma unroll
        for (int j = 0; j < 8; ++j) {
            float uA = xA[j] + xr[j];
            float uB = xB[j] + xr[j];
            uA = fmaxf(uA, SLOPE * uA);
            uB = fmaxf(uB, SLOPE * uB);
            dA = fmaf(uA, av[j], dA);
            dB = fmaf(uB, av[j], dB);
        }
        float tA = quadsum(dA);
        float tB = quadsum(dB);
        float wA = __expf(fminf(tA, 80.f));
        float wB = __expf(fminf(tB, 80.f));
        wA = vA ? wA : 0.f;
        wB = vB ? wB : 0.f;
        s += wA + wB;
        #pragma unroll
        for (int j = 0; j < 8; ++j) {
            acc[j] = fmaf(wA, xA[j], acc[j]);
            acc[j] = fmaf(wB, xB[j], acc[j]);
        }
    }

    float rs = 1.0f / s;
    if (MEAN) {
        float o[8];
        #pragma unroll
        for (int j = 0; j < 8; ++j) {
            float v = acc[j] * rs;
            v += __shfl_xor(v, 4);
            v += __shfl_xor(v, 8);
            o[j] = fmaxf(fmaf(v, 0.25f, bias[sub * 8 + j]), 0.f);
        }
        if (vd && sub < 4) {
            *(float4*)&OUT[(size_t)dst * 32 + sub * 8]     = *(float4*)&o[0];
            *(float4*)&OUT[(size_t)dst * 32 + sub * 8 + 4] = *(float4*)&o[4];
        }
    } else {
        float o[8];
        #pragma unroll
        for (int j = 0; j < 8; ++j)
            o[j] = fmaxf(fmaf(acc[j], rs, bias[sub * 8 + j]), 0.f);
        if (vd) {
            *(float4*)&OUT[(size_t)dst * 128 + sub * 8]     = *(float4*)&o[0];
            *(float4*)&OUT[(size_t)dst * 128 + sub * 8 + 4] = *(float4*)&o[4];
        }
    }
}

// ---------------- launch ----------------

extern "C" void kernel_launch(void* const* d_in, const int* in_sizes, int n_in,
                              void* d_out, int out_size, void* d_ws, size_t ws_size,
                              hipStream_t stream) {
    const float* x   = (const float*)d_in[0];
    const int*   ei  = (const int*)d_in[1];
    const float* W1l = (const float*)d_in[2];
    const float* W1r = (const float*)d_in[3];
    const float* at1 = (const float*)d_in[4];
    const float* b1  = (const float*)d_in[5];
    const float* W2l = (const float*)d_in[6];
    const float* W2r = (const float*)d_in[7];
    const float* at2 = (const float*)d_in[8];
    const float* b2  = (const float*)d_in[9];
    const float* W3l = (const float*)d_in[10];
    const float* W3r = (const float*)d_in[11];
    const float* at3 = (const float*)d_in[12];
    const float* b3  = (const float*)d_in[13];
    float* out = (float*)d_out;

    int N = in_sizes[0] / 128;
    int E = in_sizes[1] / 2;
    const int* srcv = ei;
    const int* dstv = ei + E;

    char* p = (char*)d_ws;
    auto alloc = [&](size_t bytes) -> void* {
        void* r = (void*)p;
        p += (bytes + 255) & ~(size_t)255;
        return r;
    };
    __half* XLh = (__half*)alloc((size_t)N * 128 * 2);
    float*  XR  = (float*)alloc((size_t)N * 128 * 4);
    float*  H   = (float*)alloc((size_t)N * 128 * 4);
    int* rowptr = (int*)alloc((size_t)(N + 1) * 4);
    int* deg    = (int*)alloc((size_t)N * 4);
    int* dscan  = (int*)alloc((size_t)N * 4);
    int* cursor = (int*)alloc((size_t)N * 4);
    int* bsum   = (int*)alloc(1024 * 4);
    int* boff   = (int*)alloc(1024 * 4);
    int* col    = (int*)alloc((size_t)E * 4);
    unsigned short* Wtab = (unsigned short*)alloc((size_t)6 * 65536 * 2);

    int tiles = (N + 127) / 128;
    int nfb = (N + 15) / 16;
    int eb = (E + 255) / 256;

    // 1. zero deg (memset node), then W prep + histogram co-scheduled
    hipMemsetAsync(deg, 0, (size_t)N * 4, stream);
    fat_prep<<<384 + eb, 256, 0, stream>>>(W1l, W1r, W2l, W2r, W3l, W3r, Wtab, dstv, deg, E);
    // 2. scan -> rowptr + cursor
    int nb = (N + 1023) / 1024;
    k_scan<<<nb, 256, 0, stream>>>(deg, dscan, bsum, N);
    k_scan<<<1, 256, 0, stream>>>(bsum, boff, nullptr, nb);
    k_scan_add<<<(N + 256) / 256, 256, 0, stream>>>(dscan, boff, rowptr, cursor, N, E);
    // 3. CSR fill + gemm layer 1 co-scheduled
    fat_gf<<<eb + 2 * tiles, 256, 0, stream>>>(x, Wtab, XLh, XR, N, srcv, dstv, cursor, col, E);
    // 4. attention layer 1
    fused_gat<false><<<nfb, 256, 0, stream>>>(XLh, XR, at1, b1, rowptr, col, H, N);
    // 5. layer 2
    k_gemm<<<dim3(tiles, 2), 256, 0, stream>>>(H, Wtab + 1 * 65536, XLh, XR, N);
    fused_gat<false><<<nfb, 256, 0, stream>>>(XLh, XR, at2, b2, rowptr, col, H, N);
    // 6. layer 3
    k_gemm<<<dim3(tiles, 2), 256, 0, stream>>>(H, Wtab + 2 * 65536, XLh, XR, N);
    fused_gat<true><<<nfb, 256, 0, stream>>>(XLh, XR, at3, b3, rowptr, col, out, N);
}

// Round 8
// 589.621 us; speedup vs baseline: 1.2150x; 1.2150x over previous
//
#include <hip/hip_runtime.h>
#include <hip/hip_bf16.h>
#include <hip/hip_fp16.h>

#define SLOPE 0.2f

typedef __attribute__((ext_vector_type(8))) short bf16x8;
typedef __attribute__((ext_vector_type(4))) float f32x4;

__device__ __forceinline__ unsigned short bf16_rn(float f) {
    unsigned u = __float_as_uint(f);
    return (unsigned short)((u + 0x7FFFu + ((u >> 16) & 1u)) >> 16);
}
__device__ __forceinline__ float bf16_to_f32(unsigned short s) {
    return __uint_as_float(((unsigned)s) << 16);
}

// ---------------- fat prep: W split/transpose (6 mats, linear [n][k] layout) + histogram ----

__global__ __launch_bounds__(256) void fat_prep(const float* __restrict__ W0, const float* __restrict__ W1,
                                                const float* __restrict__ W2, const float* __restrict__ W3,
                                                const float* __restrict__ W4, const float* __restrict__ W5,
                                                unsigned short* __restrict__ Wtab,
                                                const int* __restrict__ dstv, int* __restrict__ deg, int E) {
    int b = blockIdx.x, t = threadIdx.x;
    if (b < 384) {
        int j = b >> 6;                  // matrix 0..5
        int e = ((b & 63) << 8) + t;     // 0..16383
        const float* W = (j == 0) ? W0 : (j == 1) ? W1 : (j == 2) ? W2
                       : (j == 3) ? W3 : (j == 4) ? W4 : W5;
        int L = j >> 1, side = j & 1;
        unsigned short* hiT = Wtab + (size_t)L * 65536 + side * 16384;
        unsigned short* loT = hiT + 32768;
        int n = e >> 7, k = e & 127;
        float x = W[k * 128 + n];
        unsigned short h = bf16_rn(x);
        hiT[e] = h;                      // [n][k] transposed
        loT[e] = bf16_rn(x - bf16_to_f32(h));
    } else {
        int i = (b - 384) * 256 + t;     // histogram: fire-and-forget atomics
        if (i < E) atomicAdd(&deg[dstv[i]], 1);
    }
}

// ---------------- scan ----------------

__global__ __launch_bounds__(256) void k_scan(const int* __restrict__ in, int* __restrict__ out,
                                              int* bsums, int n) {
    __shared__ int wsum[4];
    int t = threadIdx.x;
    int base = blockIdx.x * 1024 + t * 4;
    int v0 = (base + 0 < n) ? in[base + 0] : 0;
    int v1 = (base + 1 < n) ? in[base + 1] : 0;
    int v2 = (base + 2 < n) ? in[base + 2] : 0;
    int v3 = (base + 3 < n) ? in[base + 3] : 0;
    int tsum = v0 + v1 + v2 + v3;
    int lane = t & 63, wid = t >> 6;
    int x = tsum;
    #pragma unroll
    for (int d = 1; d < 64; d <<= 1) {
        int y = __shfl_up(x, d);
        if (lane >= d) x += y;
    }
    if (lane == 63) wsum[wid] = x;
    __syncthreads();
    if (t == 0) {
        int a = 0;
        for (int w = 0; w < 4; ++w) { int b = wsum[w]; wsum[w] = a; a += b; }
    }
    __syncthreads();
    int excl = x - tsum + wsum[wid];
    if (base + 0 < n) out[base + 0] = excl;
    if (base + 1 < n) out[base + 1] = excl + v0;
    if (base + 2 < n) out[base + 2] = excl + v0 + v1;
    if (base + 3 < n) out[base + 3] = excl + v0 + v1 + v2;
    if (bsums != nullptr && t == 255) bsums[blockIdx.x] = excl + tsum;
}

__global__ __launch_bounds__(256) void k_scan_add(const int* __restrict__ dscan,
                                                  const int* __restrict__ boff,
                                                  int* __restrict__ rowptr, int* __restrict__ cursor,
                                                  int n, int total) {
    int i = blockIdx.x * 256 + threadIdx.x;
    if (i < n) {
        int v = dscan[i] + boff[i >> 10];
        rowptr[i] = v;
        cursor[i] = v;
    }
    if (i == n) rowptr[n] = total;
}

// ---------------- MFMA GEMM block (bf16x3): A+B staged in 40KB LDS (round-6 proven) ----

#define LDS_A_HI 0
#define LDS_A_LO 10240
#define LDS_B_HI 20480
#define LDS_B_LO 30720

__device__ __forceinline__ void gemm_block(const float* __restrict__ X,
                                           const unsigned short* __restrict__ WL,
                                           __half* __restrict__ Y0, float* __restrict__ Y1,
                                           int M, int tile, int ysel,
                                           unsigned char* lds, int t) {
    const unsigned short* whi = WL + ysel * 16384;
    const unsigned short* wlo = whi + 32768;
    int row0 = tile * 128;
    int lane = t & 63, w = t >> 6;
    int ml = lane & 15, q = lane >> 4;
    int sm = t >> 1, sh = t & 1;
    int srow = row0 + sm;
    bool svalid = srow < M;

    f32x4 acc[2][8];
    #pragma unroll
    for (int i = 0; i < 2; ++i)
        #pragma unroll
        for (int j = 0; j < 8; ++j) acc[i][j] = (f32x4){0.f, 0.f, 0.f, 0.f};

    for (int ks = 0; ks < 4; ++ks) {
        int k0 = ks * 32;
        // ---- stage A (fp32 -> bf16 hi/lo), 80B row stride ----
        {
            float v[16];
            if (svalid) {
                const float* src = X + (size_t)srow * 128 + k0 + sh * 16;
                *(float4*)&v[0]  = *(const float4*)&src[0];
                *(float4*)&v[4]  = *(const float4*)&src[4];
                *(float4*)&v[8]  = *(const float4*)&src[8];
                *(float4*)&v[12] = *(const float4*)&src[12];
            } else {
                #pragma unroll
                for (int j = 0; j < 16; ++j) v[j] = 0.f;
            }
            unsigned hw[8], lw[8];
            #pragma unroll
            for (int j = 0; j < 8; ++j) {
                unsigned short h0 = bf16_rn(v[2 * j]);
                unsigned short h1 = bf16_rn(v[2 * j + 1]);
                unsigned short l0 = bf16_rn(v[2 * j] - bf16_to_f32(h0));
                unsigned short l1 = bf16_rn(v[2 * j + 1] - bf16_to_f32(h1));
                hw[j] = (unsigned)h0 | ((unsigned)h1 << 16);
                lw[j] = (unsigned)l0 | ((unsigned)l1 << 16);
            }
            unsigned char* pa = lds + LDS_A_HI + sm * 80 + sh * 32;
            *(uint4*)(pa)      = *(uint4*)&hw[0];
            *(uint4*)(pa + 16) = *(uint4*)&hw[4];
            unsigned char* pl = lds + LDS_A_LO + sm * 80 + sh * 32;
            *(uint4*)(pl)      = *(uint4*)&lw[0];
            *(uint4*)(pl + 16) = *(uint4*)&lw[4];
        }
        // ---- stage B (straight copy of pre-split, pre-transposed W) ----
        {
            #pragma unroll
            for (int cc = 0; cc < 2; ++cc) {
                int c = t + cc * 256;
                int n = c >> 2, kc = (c & 3) * 8;
                *(uint4*)(lds + LDS_B_HI + n * 80 + (c & 3) * 16) =
                    *(const uint4*)(whi + n * 128 + k0 + kc);
                *(uint4*)(lds + LDS_B_LO + n * 80 + (c & 3) * 16) =
                    *(const uint4*)(wlo + n * 128 + k0 + kc);
            }
        }
        __syncthreads();
        bf16x8 ah[2], al[2];
        #pragma unroll
        for (int mt = 0; mt < 2; ++mt) {
            int am = w * 32 + mt * 16 + ml;
            ah[mt] = *(const bf16x8*)(lds + LDS_A_HI + am * 80 + q * 16);
            al[mt] = *(const bf16x8*)(lds + LDS_A_LO + am * 80 + q * 16);
        }
        #pragma unroll
        for (int nt = 0; nt < 8; ++nt) {
            int bn = nt * 16 + ml;
            bf16x8 bh = *(const bf16x8*)(lds + LDS_B_HI + bn * 80 + q * 16);
            bf16x8 bl = *(const bf16x8*)(lds + LDS_B_LO + bn * 80 + q * 16);
            #pragma unroll
            for (int mt = 0; mt < 2; ++mt) {
                acc[mt][nt] = __builtin_amdgcn_mfma_f32_16x16x32_bf16(ah[mt], bh, acc[mt][nt], 0, 0, 0);
                acc[mt][nt] = __builtin_amdgcn_mfma_f32_16x16x32_bf16(ah[mt], bl, acc[mt][nt], 0, 0, 0);
                acc[mt][nt] = __builtin_amdgcn_mfma_f32_16x16x32_bf16(al[mt], bh, acc[mt][nt], 0, 0, 0);
            }
        }
        __syncthreads();
    }

    if (ysel == 0) {
        #pragma unroll
        for (int mt = 0; mt < 2; ++mt) {
            int rbase = row0 + w * 32 + mt * 16 + q * 4;
            #pragma unroll
            for (int r = 0; r < 4; ++r) {
                int row = rbase + r;
                if (row < M) {
                    #pragma unroll
                    for (int nt = 0; nt < 8; ++nt)
                        Y0[(size_t)row * 128 + nt * 16 + ml] = __float2half(acc[mt][nt][r]);
                }
            }
        }
    } else {
        #pragma unroll
        for (int mt = 0; mt < 2; ++mt) {
            int rbase = row0 + w * 32 + mt * 16 + q * 4;
            #pragma unroll
            for (int r = 0; r < 4; ++r) {
                int row = rbase + r;
                if (row < M) {
                    #pragma unroll
                    for (int nt = 0; nt < 8; ++nt)
                        Y1[(size_t)row * 128 + nt * 16 + ml] = acc[mt][nt][r];
                }
            }
        }
    }
}

__global__ __launch_bounds__(256) void k_gemm(const float* __restrict__ X,
                                              const unsigned short* __restrict__ WL,
                                              __half* __restrict__ Y0, float* __restrict__ Y1, int M) {
    __shared__ __align__(16) unsigned char lds[40960];
    gemm_block(X, WL, Y0, Y1, M, blockIdx.x, blockIdx.y, lds, threadIdx.x);
}

// ---- fat: gemm layer 1 with fill embedded at instruction granularity ----
// prologue: 4 edges/thread -> issue 4 independent atomics (latency hidden by gemm k-loop)
// epilogue: scatter col stores (fire-and-forget)

__global__ __launch_bounds__(256) void fat_g1(const float* __restrict__ X,
                                              const unsigned short* __restrict__ WL,
                                              __half* __restrict__ Y0, float* __restrict__ Y1, int M,
                                              const int* __restrict__ srcv, const int* __restrict__ dstv,
                                              int* __restrict__ cursor, int* __restrict__ col, int E) {
    __shared__ __align__(16) unsigned char lds[40960];
    int tiles = (M + 127) >> 7;
    int tid = blockIdx.x * 256 + threadIdx.x;
    int T = gridDim.x * 256;

    // fill prologue: issue atomics, stash results
    int ps[4], ss[4];
    #pragma unroll
    for (int i = 0; i < 4; ++i) {
        int idx = tid + i * T;
        if (idx < E) {
            ss[i] = srcv[idx];
            ps[i] = atomicAdd(&cursor[dstv[idx]], 1);
        } else {
            ps[i] = -1;
        }
    }

    gemm_block(X, WL, Y0, Y1, M, blockIdx.x % tiles, blockIdx.x / tiles, lds, threadIdx.x);

    // fill epilogue: atomic latency long gone; scatter stores
    #pragma unroll
    for (int i = 0; i < 4; ++i)
        if (ps[i] >= 0) col[ps[i]] = ss[i];
}

// ---------------- fused attention: 4 dsts per wave, analytic self-loop ----------------

__device__ __forceinline__ float quadsum(float t) {
    t += __int_as_float(__builtin_amdgcn_update_dpp(0, __float_as_int(t), 0xB1, 0xf, 0xf, true)); // [1,0,3,2]
    t += __int_as_float(__builtin_amdgcn_update_dpp(0, __float_as_int(t), 0x4E, 0xf, 0xf, true)); // [2,3,0,1]
    return t;
}

template <bool MEAN>
__global__ __launch_bounds__(256) void fused_gat(const __half* __restrict__ XLh,
                                                 const float* __restrict__ XR,
                                                 const float* __restrict__ att,
                                                 const float* __restrict__ bias,
                                                 const int* __restrict__ rowptr,
                                                 const int* __restrict__ col,
                                                 float* __restrict__ OUT, int N) {
    int wave = (blockIdx.x * blockDim.x + threadIdx.x) >> 6;
    int lane = threadIdx.x & 63;
    int g = lane >> 4, sub = lane & 15;
    int dst = wave * 4 + g;
    bool vd = dst < N;
    int d0 = vd ? dst : 0;

    int start = vd ? rowptr[d0] : 0;
    int end   = vd ? rowptr[d0 + 1] : 0;

    float xr[8], av[8];
    {
        const float* xrp = &XR[(size_t)d0 * 128 + sub * 8];
        *(float4*)&xr[0] = *(const float4*)&xrp[0];
        *(float4*)&xr[4] = *(const float4*)&xrp[4];
        *(float4*)&av[0] = *(const float4*)&att[sub * 8];
        *(float4*)&av[4] = *(const float4*)&att[sub * 8 + 4];
    }

    int deg = end - start;
    int md = max(deg, __shfl_xor(deg, 16));
    md = max(md, __shfl_xor(md, 32));

    float acc[8];
    float s;
    // ---- analytic self-loop ----
    {
        uint4 r = *(const uint4*)&XLh[(size_t)d0 * 128 + sub * 8];
        float xs[8];
        const __half2* h = (const __half2*)&r;
        #pragma unroll
        for (int qq = 0; qq < 4; ++qq) {
            float2 f = __half22float2(h[qq]);
            xs[2 * qq] = f.x; xs[2 * qq + 1] = f.y;
        }
        float dS = 0.f;
        #pragma unroll
        for (int j = 0; j < 8; ++j) {
            float u = xs[j] + xr[j];
            u = fmaxf(u, SLOPE * u);
            dS = fmaf(u, av[j], dS);
        }
        float tS = quadsum(dS);
        float wS = __expf(fminf(tS, 80.f));
        s = wS;
        #pragma unroll
        for (int j = 0; j < 8; ++j) acc[j] = wS * xs[j];
    }

    for (int i = 0; i < md; i += 2) {
        int pA = start + i, pB = start + i + 1;
        bool vA = pA < end, vB = pB < end;
        int iA = col[vA ? pA : 0];
        int iB = col[vB ? pB : 0];
        uint4 rA = *(const uint4*)&XLh[(size_t)iA * 128 + sub * 8];
        uint4 rB = *(const uint4*)&XLh[(size_t)iB * 128 + sub * 8];
        float xA[8], xB[8];
        {
            const __half2* hA = (const __half2*)&rA;
            const __half2* hB = (const __half2*)&rB;
            #pragma unroll
            for (int qq = 0; qq < 4; ++qq) {
                float2 fA = __half22float2(hA[qq]);
                float2 fB = __half22float2(hB[qq]);
                xA[2 * qq] = fA.x; xA[2 * qq + 1] = fA.y;
                xB[2 * qq] = fB.x; xB[2 * qq + 1] = fB.y;
            }
        }
        float dA = 0.f, dB = 0.f;
        #pragma unroll
        for (int j = 0; j < 8; ++j) {
            float uA = xA[j] + xr[j];
            float uB = xB[j] + xr[j];
            uA = fmaxf(uA, SLOPE * uA);
            uB = fmaxf(uB, SLOPE * uB);
            dA = fmaf(uA, av[j], dA);
            dB = fmaf(uB, av[j], dB);
        }
        float tA = quadsum(dA);
        float tB = quadsum(dB);
        float wA = __expf(fminf(tA, 80.f));
        float wB = __expf(fminf(tB, 80.f));
        wA = vA ? wA : 0.f;
        wB = vB ? wB : 0.f;
        s += wA + wB;
        #pragma unroll
        for (int j = 0; j < 8; ++j) {
            acc[j] = fmaf(wA, xA[j], acc[j]);
            acc[j] = fmaf(wB, xB[j], acc[j]);
        }
    }

    float rs = 1.0f / s;
    if (MEAN) {
        float o[8];
        #pragma unroll
        for (int j = 0; j < 8; ++j) {
            float v = acc[j] * rs;
            v += __shfl_xor(v, 4);
            v += __shfl_xor(v, 8);
            o[j] = fmaxf(fmaf(v, 0.25f, bias[sub * 8 + j]), 0.f);
        }
        if (vd && sub < 4) {
            *(float4*)&OUT[(size_t)dst * 32 + sub * 8]     = *(float4*)&o[0];
            *(float4*)&OUT[(size_t)dst * 32 + sub * 8 + 4] = *(float4*)&o[4];
        }
    } else {
        float o[8];
        #pragma unroll
        for (int j = 0; j < 8; ++j)
            o[j] = fmaxf(fmaf(acc[j], rs, bias[sub * 8 + j]), 0.f);
        if (vd) {
            *(float4*)&OUT[(size_t)dst * 128 + sub * 8]     = *(float4*)&o[0];
            *(float4*)&OUT[(size_t)dst * 128 + sub * 8 + 4] = *(float4*)&o[4];
        }
    }
}

// ---------------- launch ----------------

extern "C" void kernel_launch(void* const* d_in, const int* in_sizes, int n_in,
                              void* d_out, int out_size, void* d_ws, size_t ws_size,
                              hipStream_t stream) {
    const float* x   = (const float*)d_in[0];
    const int*   ei  = (const int*)d_in[1];
    const float* W1l = (const float*)d_in[2];
    const float* W1r = (const float*)d_in[3];
    const float* at1 = (const float*)d_in[4];
    const float* b1  = (const float*)d_in[5];
    const float* W2l = (const float*)d_in[6];
    const float* W2r = (const float*)d_in[7];
    const float* at2 = (const float*)d_in[8];
    const float* b2  = (const float*)d_in[9];
    const float* W3l = (const float*)d_in[10];
    const float* W3r = (const float*)d_in[11];
    const float* at3 = (const float*)d_in[12];
    const float* b3  = (const float*)d_in[13];
    float* out = (float*)d_out;

    int N = in_sizes[0] / 128;
    int E = in_sizes[1] / 2;
    const int* srcv = ei;
    const int* dstv = ei + E;

    char* p = (char*)d_ws;
    auto alloc = [&](size_t bytes) -> void* {
        void* r = (void*)p;
        p += (bytes + 255) & ~(size_t)255;
        return r;
    };
    __half* XLh = (__half*)alloc((size_t)N * 128 * 2);
    float*  XR  = (float*)alloc((size_t)N * 128 * 4);
    float*  H   = (float*)alloc((size_t)N * 128 * 4);
    int* rowptr = (int*)alloc((size_t)(N + 1) * 4);
    int* deg    = (int*)alloc((size_t)N * 4);
    int* dscan  = (int*)alloc((size_t)N * 4);
    int* cursor = (int*)alloc((size_t)N * 4);
    int* bsum   = (int*)alloc(1024 * 4);
    int* boff   = (int*)alloc(1024 * 4);
    int* col    = (int*)alloc((size_t)E * 4);
    unsigned short* Wtab = (unsigned short*)alloc((size_t)6 * 65536 * 2);

    int tiles = (N + 127) / 128;
    int nfb = (N + 15) / 16;
    int eb = (E + 255) / 256;

    // 1. zero deg, then W prep + histogram co-scheduled
    hipMemsetAsync(deg, 0, (size_t)N * 4, stream);
    fat_prep<<<384 + eb, 256, 0, stream>>>(W1l, W1r, W2l, W2r, W3l, W3r, Wtab, dstv, deg, E);
    // 2. scan -> rowptr + cursor
    int nb = (N + 1023) / 1024;
    k_scan<<<nb, 256, 0, stream>>>(deg, dscan, bsum, N);
    k_scan<<<1, 256, 0, stream>>>(bsum, boff, nullptr, nb);
    k_scan_add<<<(N + 256) / 256, 256, 0, stream>>>(dscan, boff, rowptr, cursor, N, E);
    // 3. gemm layer 1 with embedded CSR fill
    fat_g1<<<2 * tiles, 256, 0, stream>>>(x, Wtab, XLh, XR, N, srcv, dstv, cursor, col, E);
    // 4. attention layer 1
    fused_gat<false><<<nfb, 256, 0, stream>>>(XLh, XR, at1, b1, rowptr, col, H, N);
    // 5. layer 2
    k_gemm<<<dim3(tiles, 2), 256, 0, stream>>>(H, Wtab + 1 * 65536, XLh, XR, N);
    fused_gat<false><<<nfb, 256, 0, stream>>>(XLh, XR, at2, b2, rowptr, col, H, N);
    // 6. layer 3
    k_gemm<<<dim3(tiles, 2), 256, 0, stream>>>(H, Wtab + 2 * 65536, XLh, XR, N);
    fused_gat<true><<<nfb, 256, 0, stream>>>(XLh, XR, at3, b3, rowptr, col, out, N);
}